// Round 1
// baseline (286.970 us; speedup 1.0000x reference)
//
#include <hip/hip_runtime.h>
#include <math.h>

#define B_ 8
#define H_ 128
#define N_ 64
#define L_ 8192

// One wave (64 threads) per (b,h) sequence. Lane = diagonal state index n.
// Tracks u+iv = w_n * s_n with s_n[l] = r_n s_n[l-1] + x[l]; out[l] = sum_n u.
// Cross-lane sum done via 64x(64+1) LDS transpose (pad +1 -> conflict-free
// column reads: (n*65+l)%32 = (n+l)%32, 2 lanes/bank = free).
__global__ __launch_bounds__(64) void s4d_scan_kernel(
    const float* __restrict__ x,
    const float* __restrict__ A_re,
    const float* __restrict__ A_im,
    const float* __restrict__ C,
    const float* __restrict__ D,
    const float* __restrict__ log_delta,
    float* __restrict__ out)
{
    __shared__ float xs[64];
    __shared__ float cbuf[64 * 65];

    const int seq  = blockIdx.x;        // b*H + h  (x is (B,H,L) row-major)
    const int h    = seq % H_;
    const int lane = threadIdx.x;       // state index n

    // ---- per-(h,n) SSM parameters (computed once, inline) ----
    float are = fminf(A_re[h * N_ + lane], -1e-4f);
    float aim = A_im[h * N_ + lane];
    float cre = C[(h * N_ + lane) * 2 + 0];
    float cim = C[(h * N_ + lane) * 2 + 1];
    float step = expf(log_delta[h]);
    float dre = step * are;
    float dim = step * aim;
    // r = exp(dA) = exp(dre) * (cos(dim) + i sin(dim))
    float er = expf(dre);
    float rr = er * cosf(dim);
    float ri = er * sinf(dim);
    // cons = (r - 1) / A   (complex divide by A = are + i*aim)
    float inv  = 1.0f / (are * are + aim * aim);
    float numr = rr - 1.0f;
    float numi = ri;
    float consr = (numr * are + numi * aim) * inv;
    float consi = (numi * are - numr * aim) * inv;
    // w = Cc * cons, Cc = cre + i*cim
    float wr = cre * consr - cim * consi;
    float wi = cre * consi + cim * consr;
    float d  = D[h];

    const float* xp = x   + (size_t)seq * L_;
    float*       op = out + (size_t)seq * L_;

    float u = 0.0f, v = 0.0f;           // u+iv = w_n * s_n
    float xv = xp[lane];                // prefetch group 0
    for (int g = 0; g < L_ / 64; ++g) {
        float xcur = xv;
        xs[lane] = xcur;
        __syncthreads();
        if (g + 1 < L_ / 64) xv = xp[(g + 1) * 64 + lane];  // prefetch next
#pragma unroll
        for (int j = 0; j < 64; ++j) {
            float xj = xs[j];           // broadcast read (same addr, free)
            float nu = fmaf(rr, u, fmaf(-ri, v, wr * xj));
            float nv = fmaf(rr, v, fmaf( ri, u, wi * xj));
            u = nu; v = nv;
            cbuf[lane * 65 + j] = nu;   // contribution Re(w*s) at step g*64+j
        }
        __syncthreads();
        // column sum: lane l accumulates output position g*64 + l
        float acc = 0.0f;
#pragma unroll
        for (int n = 0; n < 64; ++n) acc += cbuf[n * 65 + lane];
        op[g * 64 + lane] = fmaf(d, xcur, acc);   // + D*x skip
        // no third barrier needed: next iter's xs write doesn't alias cbuf,
        // and the top-of-loop barrier orders xs writes vs. inner-loop reads.
    }
}

extern "C" void kernel_launch(void* const* d_in, const int* in_sizes, int n_in,
                              void* d_out, int out_size, void* d_ws, size_t ws_size,
                              hipStream_t stream)
{
    const float* x  = (const float*)d_in[0];
    const float* Ar = (const float*)d_in[1];
    const float* Ai = (const float*)d_in[2];
    const float* C  = (const float*)d_in[3];
    const float* D  = (const float*)d_in[4];
    const float* ld = (const float*)d_in[5];
    float* out = (float*)d_out;

    dim3 grid(B_ * H_);
    dim3 block(64);
    hipLaunchKernelGGL(s4d_scan_kernel, grid, block, 0, stream,
                       x, Ar, Ai, C, D, ld, out);
}

// Round 2
// 264.810 us; speedup vs baseline: 1.0837x; 1.0837x over previous
//
#include <hip/hip_runtime.h>
#include <math.h>

#define B_ 8
#define H_ 128
#define N_ 64
#define L_ 8192
#define S_ 16
#define M_ (L_ / S_)          // 512 steps per chunk
#define NSEQ (B_ * H_)        // 1024 sequences
#define NCHUNK (NSEQ * S_)    // 16384 chunk-waves

// broadcast lane j's value to all lanes via v_readlane (VALU pipe, j constant
// under full unroll) -- keeps the LDS pipe free for the transpose buffer.
__device__ __forceinline__ float readlane_f(float v, int lane) {
    return __int_as_float(__builtin_amdgcn_readlane(__float_as_int(v), lane));
}

// per-(h,n) discrete pole r = exp(step*A)
__device__ __forceinline__ void pole(const float* A_re, const float* A_im,
                                     const float* log_delta, int h, int n,
                                     float& rr, float& ri, float& are, float& aim,
                                     float& step) {
    are = fminf(A_re[h * N_ + n], -1e-4f);
    aim = A_im[h * N_ + n];
    step = expf(log_delta[h]);
    float dre = step * are, dim = step * aim;
    float er = expf(dre);
    rr = er * cosf(dim);
    ri = er * sinf(dim);
}

// ---- K1: per (seq,chunk) zero-init end state e_c = sum_j r^{M-1-j} x[j] ----
// 4 waves per block (no LDS, no syncs) for full occupancy.
__global__ __launch_bounds__(256) void k1_chunk_end(
    const float* __restrict__ x, const float* __restrict__ A_re,
    const float* __restrict__ A_im, const float* __restrict__ log_delta,
    float2* __restrict__ e)
{
    const int wid  = blockIdx.x * 4 + (threadIdx.x >> 6);  // seq*S + c
    const int lane = threadIdx.x & 63;
    const int seq  = wid / S_;
    const int c    = wid % S_;
    const int h    = seq % H_;

    float rr, ri, are, aim, step;
    pole(A_re, A_im, log_delta, h, lane, rr, ri, are, aim, step);

    const float* xp = x + (size_t)seq * L_ + c * M_;
    float u = 0.f, v = 0.f;
    float xv = xp[lane];                      // prefetch group 0
    for (int g = 0; g < M_ / 64; ++g) {
        float xcur = xv;
        if (g + 1 < M_ / 64) xv = xp[(g + 1) * 64 + lane];
#pragma unroll
        for (int j = 0; j < 64; ++j) {
            float xj = readlane_f(xcur, j);
            float nu = fmaf(rr, u, fmaf(-ri, v, xj));
            float nv = fmaf(rr, v, ri * u);
            u = nu; v = nv;
        }
    }
    e[(size_t)wid * N_ + lane] = make_float2(u, v);
}

// ---- K2: chunk-level exclusive scan (in-place): s_init_{c+1} = e_c + r^M s_init_c
__global__ __launch_bounds__(256) void k2_scan(
    const float* __restrict__ A_re, const float* __restrict__ A_im,
    const float* __restrict__ log_delta, float2* __restrict__ e)
{
    const int t   = blockIdx.x * 256 + threadIdx.x;   // [0, NSEQ*N)
    const int n   = t & (N_ - 1);
    const int seq = t >> 6;
    const int h   = seq % H_;

    float rr, ri, are, aim, step;
    pole(A_re, A_im, log_delta, h, n, rr, ri, are, aim, step);

    // r^M via 9 squarings (M = 512 = 2^9)
    float mr = rr, mi = ri;
#pragma unroll
    for (int k = 0; k < 9; ++k) {
        float tr = mr * mr - mi * mi;
        float ti = 2.f * mr * mi;
        mr = tr; mi = ti;
    }

    float ar = 0.f, ai = 0.f;                 // exclusive prefix (s_init_0 = 0)
#pragma unroll
    for (int c = 0; c < S_; ++c) {
        size_t idx = ((size_t)seq * S_ + c) * N_ + n;
        float2 ec = e[idx];
        e[idx] = make_float2(ar, ai);         // overwrite e with s_init
        float nr = ec.x + (mr * ar - mi * ai);
        float ni = ec.y + (mr * ai + mi * ar);
        ar = nr; ai = ni;
    }
}

// ---- K3: per (seq,chunk) output pass, state seeded with w * s_init ----
__global__ __launch_bounds__(64) void k3_out(
    const float* __restrict__ x, const float* __restrict__ A_re,
    const float* __restrict__ A_im, const float* __restrict__ C,
    const float* __restrict__ D, const float* __restrict__ log_delta,
    const float2* __restrict__ sinit, float* __restrict__ out)
{
    __shared__ float cbuf[64 * 65];           // +1 pad: 2 lanes/bank = free

    const int wid  = blockIdx.x;              // seq*S + c
    const int lane = threadIdx.x;
    const int seq  = wid / S_;
    const int c    = wid % S_;
    const int h    = seq % H_;

    float rr, ri, are, aim, step;
    pole(A_re, A_im, log_delta, h, lane, rr, ri, are, aim, step);

    // w = Cc * (r-1)/A
    float cre = C[(h * N_ + lane) * 2 + 0];
    float cim = C[(h * N_ + lane) * 2 + 1];
    float inv  = 1.0f / (are * are + aim * aim);
    float numr = rr - 1.0f, numi = ri;
    float consr = (numr * are + numi * aim) * inv;
    float consi = (numi * are - numr * aim) * inv;
    float wr = cre * consr - cim * consi;
    float wi = cre * consi + cim * consr;
    float d  = D[h];

    // seed folded state uv = w * s_init
    float2 s0 = sinit[(size_t)wid * N_ + lane];
    float u = wr * s0.x - wi * s0.y;
    float v = wr * s0.y + wi * s0.x;

    const float* xp = x   + (size_t)seq * L_ + c * M_;
    float*       op = out + (size_t)seq * L_ + c * M_;

    float xv = xp[lane];                      // prefetch group 0
    for (int g = 0; g < M_ / 64; ++g) {
        float xcur = xv;
        if (g + 1 < M_ / 64) xv = xp[(g + 1) * 64 + lane];
#pragma unroll
        for (int j = 0; j < 64; ++j) {
            float xj = readlane_f(xcur, j);
            float nu = fmaf(rr, u, fmaf(-ri, v, wr * xj));
            float nv = fmaf(rr, v, fmaf(ri, u, wi * xj));
            u = nu; v = nv;
            cbuf[lane * 65 + j] = nu;         // Re(w*s) contribution
        }
        __syncthreads();
        float acc = 0.f;
#pragma unroll
        for (int n = 0; n < 64; ++n) acc += cbuf[n * 65 + lane];
        op[g * 64 + lane] = fmaf(d, xcur, acc);
        __syncthreads();                      // protect cbuf before next group's writes
    }
}

extern "C" void kernel_launch(void* const* d_in, const int* in_sizes, int n_in,
                              void* d_out, int out_size, void* d_ws, size_t ws_size,
                              hipStream_t stream)
{
    const float* x  = (const float*)d_in[0];
    const float* Ar = (const float*)d_in[1];
    const float* Ai = (const float*)d_in[2];
    const float* C  = (const float*)d_in[3];
    const float* D  = (const float*)d_in[4];
    const float* ld = (const float*)d_in[5];
    float* out = (float*)d_out;
    float2* e = (float2*)d_ws;                // B*H*S*N complex = 8.4 MB

    hipLaunchKernelGGL(k1_chunk_end, dim3(NCHUNK / 4), dim3(256), 0, stream,
                       x, Ar, Ai, ld, e);
    hipLaunchKernelGGL(k2_scan, dim3(NSEQ * N_ / 256), dim3(256), 0, stream,
                       Ar, Ai, ld, e);
    hipLaunchKernelGGL(k3_out, dim3(NCHUNK), dim3(64), 0, stream,
                       x, Ar, Ai, C, D, ld, e, out);
}

// Round 3
// 126.767 us; speedup vs baseline: 2.2638x; 2.0890x over previous
//
#include <hip/hip_runtime.h>
#include <math.h>

#define B_ 8
#define H_ 128
#define N_ 64
#define L_ 8192
#define MCH 64                 // chunk length
#define SCH (L_ / MCH)         // 128 chunks per sequence
#define EROW 136               // EBUF row stride (bf16 elems): 272 B, 16B-aligned

typedef __attribute__((ext_vector_type(8))) short bf16x8;  // MFMA A/B frag (4 VGPR)
typedef __attribute__((ext_vector_type(4))) float f32x4;   // MFMA C/D frag

__device__ __forceinline__ ushort f2bf(float f) {          // RNE fp32->bf16
    uint u = __float_as_uint(f);
    return (ushort)((u + 0x7fffu + ((u >> 16) & 1u)) >> 16);
}
__device__ __forceinline__ float bf2f(ushort s) { return __uint_as_float(((uint)s) << 16); }
__device__ __forceinline__ uint packbf2(float a, float b) {
    return (uint)f2bf(a) | ((uint)f2bf(b) << 16);
}
__device__ __forceinline__ bf16x8 pack_bf8(float4 a, float4 b) {
    bf16x8 r;
    r[0] = (short)f2bf(a.x); r[1] = (short)f2bf(a.y); r[2] = (short)f2bf(a.z); r[3] = (short)f2bf(a.w);
    r[4] = (short)f2bf(b.x); r[5] = (short)f2bf(b.y); r[6] = (short)f2bf(b.z); r[7] = (short)f2bf(b.w);
    return r;
}

// ===================== P0: build per-head T, P, Q, r^M ======================
// T[h][64][64]  bf16: T[j][t] = K[j-t] (t<=j) + D on diag;  K[d] = Re(sum_n w_n r_n^d)
// P[h][64][128] bf16: P[j][2n] = Re(w r^{j+1}),  P[j][2n+1] = -Im(w r^{j+1})
// Q[h][128][64] bf16: Q[2n][t] = Re(r^{63-t}),   Q[2n+1][t] = Im(r^{63-t})
// RM[h][64] float2: r^64
__global__ __launch_bounds__(64) void s4d_build(
    const float* __restrict__ A_re, const float* __restrict__ A_im,
    const float* __restrict__ C, const float* __restrict__ D,
    const float* __restrict__ log_delta,
    ushort* __restrict__ wsT, ushort* __restrict__ wsP,
    ushort* __restrict__ wsQ, float2* __restrict__ wsRM)
{
    __shared__ float cbuf[64 * 65];
    __shared__ float kv[64];
    __shared__ uint  pbuf[64 * 68];

    const int h = blockIdx.x, n = threadIdx.x;

    float are = fminf(A_re[h * N_ + n], -1e-4f);
    float aim = A_im[h * N_ + n];
    float step = expf(log_delta[h]);
    float dre = step * are, dim = step * aim;
    float er = expf(dre);
    float rr = er * cosf(dim);
    float ri = er * sinf(dim);
    // w = Cc * (r-1)/A
    float cre = C[(h * N_ + n) * 2 + 0];
    float cim = C[(h * N_ + n) * 2 + 1];
    float inv  = 1.0f / (are * are + aim * aim);
    float numr = rr - 1.0f, numi = ri;
    float consr = (numr * are + numi * aim) * inv;
    float consi = (numi * are - numr * aim) * inv;
    float wr = cre * consr - cim * consi;
    float wi = cre * consi + cim * consr;
    float dval = D[h];

    // r^64 by 6 squarings
    float mr = rr, mi = ri;
#pragma unroll
    for (int k = 0; k < 6; ++k) { float tr = mr*mr - mi*mi, ti = 2.f*mr*mi; mr = tr; mi = ti; }
    wsRM[h * 64 + n] = make_float2(mr, mi);

    // K[d] via transpose-sum: cbuf[n][d] = Re(w r^d)
    float pr = wr, pi = wi;
#pragma unroll
    for (int d = 0; d < 64; ++d) {
        cbuf[n * 65 + d] = pr;
        float tr = pr*rr - pi*ri, ti = pr*ri + pi*rr;
        pr = tr; pi = ti;
    }
    __syncthreads();
    float ks = 0.f;
#pragma unroll
    for (int m = 0; m < 64; ++m) ks += cbuf[m * 65 + n];
    kv[n] = ks;                       // lane n holds K[n]
    __syncthreads();

    // T row j=n (coalesced 128B row stores)
    uint trow[32];
#pragma unroll
    for (int t = 0; t < 64; t += 2) {
        float v0 = (t     <= n) ? kv[n - t]     : 0.f;
        float v1 = (t + 1 <= n) ? kv[n - t - 1] : 0.f;
        if (t == n)     v0 += dval;
        if (t + 1 == n) v1 += dval;
        trow[t >> 1] = packbf2(v0, v1);
    }
    uint4* dT = (uint4*)(wsT + ((size_t)h * 64 + n) * 64);
#pragma unroll
    for (int i = 0; i < 8; ++i) dT[i] = ((uint4*)trow)[i];

    // Q rows 2n (Re), 2n+1 (Im): r^{63-t}
    union { ushort u[64]; uint4 v4[8]; } qre, qim;
    float ppr = 1.f, ppi = 0.f;
#pragma unroll
    for (int i = 0; i < 64; ++i) {
        qre.u[63 - i] = f2bf(ppr);
        qim.u[63 - i] = f2bf(ppi);
        float tr = ppr*rr - ppi*ri, ti = ppr*ri + ppi*rr;
        ppr = tr; ppi = ti;
    }
    uint4* dQ0 = (uint4*)(wsQ + ((size_t)h * 128 + 2*n    ) * 64);
    uint4* dQ1 = (uint4*)(wsQ + ((size_t)h * 128 + 2*n + 1) * 64);
#pragma unroll
    for (int i = 0; i < 8; ++i) { dQ0[i] = qre.v4[i]; dQ1[i] = qim.v4[i]; }

    // P via LDS transpose: lane n owns column pair 2n,2n+1; u = w*r^{j+1}
    float uur = wr*rr - wi*ri, uui = wr*ri + wi*rr;
#pragma unroll
    for (int j = 0; j < 64; ++j) {
        pbuf[j * 68 + n] = packbf2(uur, -uui);
        float tr = uur*rr - uui*ri, ti = uur*ri + uui*rr;
        uur = tr; uui = ti;
    }
    __syncthreads();
    uint4* dP = (uint4*)(wsP + ((size_t)h * 64 + n) * 128);
#pragma unroll
    for (int i = 0; i < 16; ++i) dP[i] = *(const uint4*)&pbuf[n * 68 + i * 4];
}

// ===================== main: per-(b,h) fused A/B/C ==========================
__global__ __launch_bounds__(256) void s4d_main(
    const float* __restrict__ x,
    const ushort* __restrict__ wsT, const ushort* __restrict__ wsP,
    const ushort* __restrict__ wsQ, const float2* __restrict__ wsRM,
    float* __restrict__ out)
{
    __shared__ ushort EBUF[SCH * EROW];     // 128 x 136 bf16 = 34.8 KB

    const int seq = blockIdx.x;             // b*H + h
    const int h   = seq % H_;
    const int tid = threadIdx.x;
    const int w   = tid >> 6;               // wave 0..3 -> col-tiles 2w, 2w+1
    const int lane = tid & 63;
    const int n16 = lane & 15, q = lane >> 4;

    const float* xs = x + (size_t)seq * L_;

    // ---- load & convert this wave's X B-frags (kept in regs for A and C) ----
    bf16x8 xb[2][2];
#pragma unroll
    for (int ic = 0; ic < 2; ++ic) {
        int c = (2 * w + ic) * 16 + n16;    // chunk index = GEMM column
#pragma unroll
        for (int kc = 0; kc < 2; ++kc) {    // k = kc*32 + q*8 + j  (t within chunk)
            const float* p = xs + c * MCH + kc * 32 + q * 8;
            float4 f0 = *(const float4*)p;
            float4 f1 = *(const float4*)(p + 4);
            xb[ic][kc] = pack_bf8(f0, f1);
        }
    }

    // ---- Phase A: E = Q * X  (rows k=0..127, cols c) ----
    const ushort* Qh = wsQ + (size_t)h * 128 * 64;
#pragma unroll
    for (int ic = 0; ic < 2; ++ic) {
        int c = (2 * w + ic) * 16 + n16;
#pragma unroll
        for (int rt = 0; rt < 8; ++rt) {
            f32x4 acc = {0.f, 0.f, 0.f, 0.f};
#pragma unroll
            for (int kc = 0; kc < 2; ++kc) {
                bf16x8 a = *(const bf16x8*)(Qh + ((size_t)(rt * 16 + n16)) * 64 + kc * 32 + q * 8);
                acc = __builtin_amdgcn_mfma_f32_16x16x32_bf16(a, xb[ic][kc], acc, 0, 0, 0);
            }
            // D-frag: col = n16 (c), rows = rt*16 + q*4 + reg  -> EBUF[c][k]
            ushort4 st;
            st.x = f2bf(acc[0]); st.y = f2bf(acc[1]); st.z = f2bf(acc[2]); st.w = f2bf(acc[3]);
            *(ushort4*)&EBUF[c * EROW + rt * 16 + q * 4] = st;
        }
    }
    __syncthreads();

    // ---- Phase B: exclusive chunk scan, in place (threads 0..63) ----
    if (tid < 64) {
        float2 rm = wsRM[h * 64 + tid];
        float sr = 0.f, si = 0.f;
        for (int c = 0; c < SCH; ++c) {
            uint* ep = (uint*)&EBUF[c * EROW + 2 * tid];
            uint e = *ep;
            float er2 = bf2f((ushort)(e & 0xffffu));
            float ei2 = bf2f((ushort)(e >> 16));
            *ep = packbf2(sr, si);          // SV[c] = state BEFORE chunk c
            float nr = er2 + rm.x * sr - rm.y * si;
            float ni = ei2 + rm.x * si + rm.y * sr;
            sr = nr; si = ni;
        }
    }
    __syncthreads();

    // ---- Phase C: OUT = T*X + P*SV ----
    const ushort* Th = wsT + (size_t)h * 64 * 64;
    const ushort* Ph = wsP + (size_t)h * 64 * 128;
    float* op = out + (size_t)seq * L_;
#pragma unroll
    for (int ic = 0; ic < 2; ++ic) {
        int c = (2 * w + ic) * 16 + n16;
        bf16x8 svb[4];
#pragma unroll
        for (int kc = 0; kc < 4; ++kc)      // k = 2n-state index 0..127
            svb[kc] = *(const bf16x8*)&EBUF[c * EROW + kc * 32 + q * 8];
#pragma unroll
        for (int rt = 0; rt < 4; ++rt) {
            f32x4 acc = {0.f, 0.f, 0.f, 0.f};
#pragma unroll
            for (int kc = 0; kc < 2; ++kc) {
                bf16x8 a = *(const bf16x8*)(Th + ((size_t)(rt * 16 + n16)) * 64 + kc * 32 + q * 8);
                acc = __builtin_amdgcn_mfma_f32_16x16x32_bf16(a, xb[ic][kc], acc, 0, 0, 0);
            }
#pragma unroll
            for (int kc = 0; kc < 4; ++kc) {
                bf16x8 a = *(const bf16x8*)(Ph + ((size_t)(rt * 16 + n16)) * 128 + kc * 32 + q * 8);
                acc = __builtin_amdgcn_mfma_f32_16x16x32_bf16(a, svb[kc], acc, 0, 0, 0);
            }
            // rows j = rt*16 + q*4 + reg, col c -> out[seq][c*64 + j], float4
            float4 o = make_float4(acc[0], acc[1], acc[2], acc[3]);
            *(float4*)(op + c * MCH + rt * 16 + q * 4) = o;
        }
    }
}

extern "C" void kernel_launch(void* const* d_in, const int* in_sizes, int n_in,
                              void* d_out, int out_size, void* d_ws, size_t ws_size,
                              hipStream_t stream)
{
    const float* x  = (const float*)d_in[0];
    const float* Ar = (const float*)d_in[1];
    const float* Ai = (const float*)d_in[2];
    const float* C  = (const float*)d_in[3];
    const float* D  = (const float*)d_in[4];
    const float* ld = (const float*)d_in[5];
    float* out = (float*)d_out;

    ushort* wsT = (ushort*)d_ws;                 // 128*64*64   bf16 = 1 MB
    ushort* wsP = wsT + (size_t)128 * 64 * 64;   // 128*64*128  bf16 = 2 MB
    ushort* wsQ = wsP + (size_t)128 * 64 * 128;  // 128*128*64  bf16 = 2 MB
    float2* wsRM = (float2*)(wsQ + (size_t)128 * 128 * 64);  // 64 KB

    hipLaunchKernelGGL(s4d_build, dim3(H_), dim3(64), 0, stream,
                       Ar, Ai, C, D, ld, wsT, wsP, wsQ, wsRM);
    hipLaunchKernelGGL(s4d_main, dim3(B_ * H_), dim3(256), 0, stream,
                       x, wsT, wsP, wsQ, wsRM, out);
}

// Round 4
// 122.639 us; speedup vs baseline: 2.3400x; 1.0337x over previous
//
#include <hip/hip_runtime.h>
#include <math.h>

#define B_ 8
#define H_ 128
#define N_ 64
#define L_ 8192
#define MCH 64                 // chunk length
#define SCH (L_ / MCH)         // 128 chunks per sequence
#define EROW 136               // EBUF row stride (bf16 elems): 272 B, 16B-aligned

typedef __attribute__((ext_vector_type(8))) short bf16x8;  // MFMA A/B frag (4 VGPR)
typedef __attribute__((ext_vector_type(4))) float f32x4;   // MFMA C/D frag

__device__ __forceinline__ ushort f2bf(float f) {          // RNE fp32->bf16
    uint u = __float_as_uint(f);
    return (ushort)((u + 0x7fffu + ((u >> 16) & 1u)) >> 16);
}
__device__ __forceinline__ float bf2f(ushort s) { return __uint_as_float(((uint)s) << 16); }
__device__ __forceinline__ uint packbf2(float a, float b) {
    return (uint)f2bf(a) | ((uint)f2bf(b) << 16);
}
__device__ __forceinline__ bf16x8 pack_bf8(float4 a, float4 b) {
    bf16x8 r;
    r[0] = (short)f2bf(a.x); r[1] = (short)f2bf(a.y); r[2] = (short)f2bf(a.z); r[3] = (short)f2bf(a.w);
    r[4] = (short)f2bf(b.x); r[5] = (short)f2bf(b.y); r[6] = (short)f2bf(b.z); r[7] = (short)f2bf(b.w);
    return r;
}

// ===================== P0: build per-head T, P, Q, r^M ======================
// Chain-free: r^d = exp(d*dre) * cis(d*dim) computed directly per element
// (identical formulation to the reference's exp(times*dA)).
// 256 threads/head: n = tid&63 (state), g = tid>>6 (16-element power slice).
__global__ __launch_bounds__(256) void s4d_build(
    const float* __restrict__ A_re, const float* __restrict__ A_im,
    const float* __restrict__ C, const float* __restrict__ D,
    const float* __restrict__ log_delta,
    ushort* __restrict__ wsT, ushort* __restrict__ wsP,
    ushort* __restrict__ wsQ, float2* __restrict__ wsRM)
{
    __shared__ float kpart[64][65];
    __shared__ float kv[64];
    __shared__ uint  pbuf[64 * 68];

    const int h = blockIdx.x;
    const int tid = threadIdx.x;
    const int n = tid & 63;
    const int g = tid >> 6;

    float are = fminf(A_re[h * N_ + n], -1e-4f);
    float aim = A_im[h * N_ + n];
    float step = expf(log_delta[h]);
    float dre = step * are, dim = step * aim;
    float er = expf(dre);
    float rr = er * cosf(dim);
    float ri = er * sinf(dim);
    float cre = C[(h * N_ + n) * 2 + 0];
    float cim = C[(h * N_ + n) * 2 + 1];
    float inv  = 1.0f / (are * are + aim * aim);
    float numr = rr - 1.0f, numi = ri;
    float consr = (numr * are + numi * aim) * inv;
    float consi = (numi * are - numr * aim) * inv;
    float wr = cre * consr - cim * consi;
    float wi = cre * consi + cim * consr;
    float dval = D[h];

    // r^d directly (no serial chain)
    auto rp = [&](float d, float& pr, float& pi) {
        float e = expf(d * dre);
        float s, c2; sincosf(d * dim, &s, &c2);
        pr = e * c2; pi = e * s;
    };

    // ---- K[d] = Re(sum_n w r^d): kpart[d][n], then column-sum ----
#pragma unroll
    for (int j = 0; j < 16; ++j) {
        int d = g * 16 + j;
        float pr, pi; rp((float)d, pr, pi);
        kpart[d][n] = wr * pr - wi * pi;
    }
    __syncthreads();
    if (tid < 64) {
        float s = 0.f;
#pragma unroll
        for (int m = 0; m < 64; ++m) s += kpart[tid][m];
        kv[tid] = s;
    }
    __syncthreads();

    // ---- T row n, cols [16g, 16g+16): K[n-t] + D on diag ----
    {
        uint tw[8];
#pragma unroll
        for (int i = 0; i < 8; ++i) {
            int t0 = g * 16 + 2 * i, t1 = t0 + 1;
            float v0 = (t0 <= n) ? kv[n - t0] : 0.f;
            float v1 = (t1 <= n) ? kv[n - t1] : 0.f;
            if (t0 == n) v0 += dval;
            if (t1 == n) v1 += dval;
            tw[i] = packbf2(v0, v1);
        }
        uint4* dT = (uint4*)(wsT + ((size_t)h * 64 + n) * 64 + g * 16);
        dT[0] = ((uint4*)tw)[0]; dT[1] = ((uint4*)tw)[1];
    }

    // ---- Q rows 2n (Re), 2n+1 (Im), cols [16g,16g+16): r^{63-t} ----
    {
        uint qr[8], qi[8];
#pragma unroll
        for (int i = 0; i < 8; ++i) {
            int t0 = g * 16 + 2 * i;
            float ar0, ai0, ar1, ai1;
            rp((float)(63 - t0), ar0, ai0);
            rp((float)(62 - t0), ar1, ai1);
            qr[i] = packbf2(ar0, ar1);
            qi[i] = packbf2(ai0, ai1);
        }
        uint4* dQ0 = (uint4*)(wsQ + ((size_t)h * 128 + 2 * n    ) * 64 + g * 16);
        uint4* dQ1 = (uint4*)(wsQ + ((size_t)h * 128 + 2 * n + 1) * 64 + g * 16);
        dQ0[0] = ((uint4*)qr)[0]; dQ0[1] = ((uint4*)qr)[1];
        dQ1[0] = ((uint4*)qi)[0]; dQ1[1] = ((uint4*)qi)[1];
    }

    // ---- P[j][2n] = Re(w r^{j+1}), [2n+1] = -Im(w r^{j+1}), via LDS transpose
#pragma unroll
    for (int i = 0; i < 16; ++i) {
        int j = g * 16 + i;
        float pr, pi; rp((float)(j + 1), pr, pi);
        float ur = wr * pr - wi * pi;
        float ui = wr * pi + wi * pr;
        pbuf[j * 68 + n] = packbf2(ur, -ui);
    }
    if (tid < 64) {          // r^64 for the chunk scan
        float mr, mi; rp(64.f, mr, mi);
        wsRM[h * 64 + n] = make_float2(mr, mi);
    }
    __syncthreads();
    {
        uint4* dP = (uint4*)(wsP + ((size_t)h * 64 + n) * 128 + g * 32);
        const uint* src = &pbuf[n * 68 + g * 16];
        dP[0] = *(const uint4*)(src);
        dP[1] = *(const uint4*)(src + 4);
        dP[2] = *(const uint4*)(src + 8);
        dP[3] = *(const uint4*)(src + 12);
    }
}

// ===================== main: per-(b,h) fused A/B/C ==========================
__global__ __launch_bounds__(256, 4) void s4d_main(
    const float* __restrict__ x,
    const ushort* __restrict__ wsT, const ushort* __restrict__ wsP,
    const ushort* __restrict__ wsQ, const float2* __restrict__ wsRM,
    float* __restrict__ out)
{
    __shared__ ushort EBUF[SCH * EROW];     // 128 x 136 bf16 = 34.8 KB
    __shared__ float segr[4][64], segi[4][64];  // 2 KB

    const int seq = blockIdx.x;             // b*H + h  (all 8 b's of head h land on same XCD)
    const int h   = seq % H_;
    const int tid = threadIdx.x;
    const int w   = tid >> 6;               // wave 0..3 -> col-tiles 2w, 2w+1
    const int lane = tid & 63;
    const int n16 = lane & 15, q = lane >> 4;

    const float* xs = x + (size_t)seq * L_;

    // ---- X B-frags (kept in regs for phases A and C) ----
    bf16x8 xb[2][2];
#pragma unroll
    for (int ic = 0; ic < 2; ++ic) {
        int c = (2 * w + ic) * 16 + n16;    // chunk index = GEMM column
#pragma unroll
        for (int kc = 0; kc < 2; ++kc) {
            const float* p = xs + c * MCH + kc * 32 + q * 8;
            float4 f0 = *(const float4*)p;
            float4 f1 = *(const float4*)(p + 4);
            xb[ic][kc] = pack_bf8(f0, f1);
        }
    }

    // ---- Phase A: E = Q * X  (A-frags loaded once, shared across ic) ----
    const ushort* Qh = wsQ + (size_t)h * 128 * 64;
#pragma unroll
    for (int rt = 0; rt < 8; ++rt) {
        bf16x8 a0 = *(const bf16x8*)(Qh + ((size_t)(rt * 16 + n16)) * 64 +      q * 8);
        bf16x8 a1 = *(const bf16x8*)(Qh + ((size_t)(rt * 16 + n16)) * 64 + 32 + q * 8);
#pragma unroll
        for (int ic = 0; ic < 2; ++ic) {
            f32x4 acc = {0.f, 0.f, 0.f, 0.f};
            acc = __builtin_amdgcn_mfma_f32_16x16x32_bf16(a0, xb[ic][0], acc, 0, 0, 0);
            acc = __builtin_amdgcn_mfma_f32_16x16x32_bf16(a1, xb[ic][1], acc, 0, 0, 0);
            int c = (2 * w + ic) * 16 + n16;
            ushort4 st;
            st.x = f2bf(acc[0]); st.y = f2bf(acc[1]); st.z = f2bf(acc[2]); st.w = f2bf(acc[3]);
            *(ushort4*)&EBUF[c * EROW + rt * 16 + q * 4] = st;
        }
    }
    __syncthreads();

    // ---- Phase B: segmented exclusive chunk scan, all 256 threads ----
    // thread (nB, gB): nB = state, gB = segment of 32 chunks
    {
        const int nB = tid & 63, gB = tid >> 6;
        float2 rm = wsRM[h * 64 + nB];
        float mr = rm.x, mi = rm.y;
        float m32r = mr, m32i = mi;        // r^2048 via 5 squarings
#pragma unroll
        for (int k = 0; k < 5; ++k) {
            float tr = m32r * m32r - m32i * m32i, ti = 2.f * m32r * m32i;
            m32r = tr; m32i = ti;
        }
        // pass 1: zero-init segment end
        float sr = 0.f, si = 0.f;
#pragma unroll
        for (int j = 0; j < 32; ++j) {
            uint e = *(const uint*)&EBUF[(gB * 32 + j) * EROW + 2 * nB];
            float er2 = bf2f((ushort)(e & 0xffffu)), ei2 = bf2f((ushort)(e >> 16));
            float nr = er2 + mr * sr - mi * si;
            float ni = ei2 + mr * si + mi * sr;
            sr = nr; si = ni;
        }
        segr[gB][nB] = sr; segi[gB][nB] = si;
        __syncthreads();
        // exclusive prefix over segments (<=3 iters, wave-uniform trip count)
        float pr2 = 0.f, pi2 = 0.f;
        for (int gp = 0; gp < gB; ++gp) {
            float Er = segr[gp][nB], Ei = segi[gp][nB];
            float nr = Er + m32r * pr2 - m32i * pi2;
            float ni = Ei + m32r * pi2 + m32i * pr2;
            pr2 = nr; pi2 = ni;
        }
        // pass 2: replay, writing SV (state BEFORE chunk) in place
        sr = pr2; si = pi2;
#pragma unroll
        for (int j = 0; j < 32; ++j) {
            uint* ep = (uint*)&EBUF[(gB * 32 + j) * EROW + 2 * nB];
            uint e = *ep;
            float er2 = bf2f((ushort)(e & 0xffffu)), ei2 = bf2f((ushort)(e >> 16));
            *ep = packbf2(sr, si);
            float nr = er2 + mr * sr - mi * si;
            float ni = ei2 + mr * si + mi * sr;
            sr = nr; si = ni;
        }
    }
    __syncthreads();

    // ---- Phase C: OUT = T*X + P*SV (A-frags loaded once, shared across ic) --
    const ushort* Th = wsT + (size_t)h * 64 * 64;
    const ushort* Ph = wsP + (size_t)h * 64 * 128;
    float* op = out + (size_t)seq * L_;

    bf16x8 svb[2][4];
#pragma unroll
    for (int ic = 0; ic < 2; ++ic) {
        int c = (2 * w + ic) * 16 + n16;
#pragma unroll
        for (int kc = 0; kc < 4; ++kc)
            svb[ic][kc] = *(const bf16x8*)&EBUF[c * EROW + kc * 32 + q * 8];
    }
#pragma unroll
    for (int rt = 0; rt < 4; ++rt) {
        bf16x8 t0 = *(const bf16x8*)(Th + ((size_t)(rt * 16 + n16)) * 64 +      q * 8);
        bf16x8 t1 = *(const bf16x8*)(Th + ((size_t)(rt * 16 + n16)) * 64 + 32 + q * 8);
        bf16x8 p0 = *(const bf16x8*)(Ph + ((size_t)(rt * 16 + n16)) * 128 +       q * 8);
        bf16x8 p1 = *(const bf16x8*)(Ph + ((size_t)(rt * 16 + n16)) * 128 +  32 + q * 8);
        bf16x8 p2 = *(const bf16x8*)(Ph + ((size_t)(rt * 16 + n16)) * 128 +  64 + q * 8);
        bf16x8 p3 = *(const bf16x8*)(Ph + ((size_t)(rt * 16 + n16)) * 128 +  96 + q * 8);
#pragma unroll
        for (int ic = 0; ic < 2; ++ic) {
            f32x4 acc = {0.f, 0.f, 0.f, 0.f};
            acc = __builtin_amdgcn_mfma_f32_16x16x32_bf16(t0, xb[ic][0], acc, 0, 0, 0);
            acc = __builtin_amdgcn_mfma_f32_16x16x32_bf16(t1, xb[ic][1], acc, 0, 0, 0);
            acc = __builtin_amdgcn_mfma_f32_16x16x32_bf16(p0, svb[ic][0], acc, 0, 0, 0);
            acc = __builtin_amdgcn_mfma_f32_16x16x32_bf16(p1, svb[ic][1], acc, 0, 0, 0);
            acc = __builtin_amdgcn_mfma_f32_16x16x32_bf16(p2, svb[ic][2], acc, 0, 0, 0);
            acc = __builtin_amdgcn_mfma_f32_16x16x32_bf16(p3, svb[ic][3], acc, 0, 0, 0);
            int c = (2 * w + ic) * 16 + n16;
            float4 o = make_float4(acc[0], acc[1], acc[2], acc[3]);
            *(float4*)(op + c * MCH + rt * 16 + q * 4) = o;
        }
    }
}

extern "C" void kernel_launch(void* const* d_in, const int* in_sizes, int n_in,
                              void* d_out, int out_size, void* d_ws, size_t ws_size,
                              hipStream_t stream)
{
    const float* x  = (const float*)d_in[0];
    const float* Ar = (const float*)d_in[1];
    const float* Ai = (const float*)d_in[2];
    const float* C  = (const float*)d_in[3];
    const float* D  = (const float*)d_in[4];
    const float* ld = (const float*)d_in[5];
    float* out = (float*)d_out;

    ushort* wsT = (ushort*)d_ws;                 // 128*64*64   bf16 = 1 MB
    ushort* wsP = wsT + (size_t)128 * 64 * 64;   // 128*64*128  bf16 = 2 MB
    ushort* wsQ = wsP + (size_t)128 * 64 * 128;  // 128*128*64  bf16 = 2 MB
    float2* wsRM = (float2*)(wsQ + (size_t)128 * 128 * 64);  // 64 KB

    hipLaunchKernelGGL(s4d_build, dim3(H_), dim3(256), 0, stream,
                       Ar, Ai, C, D, ld, wsT, wsP, wsQ, wsRM);
    hipLaunchKernelGGL(s4d_main, dim3(B_ * H_), dim3(256), 0, stream,
                       x, wsT, wsP, wsQ, wsRM, out);
}

// Round 5
// 121.383 us; speedup vs baseline: 2.3642x; 1.0103x over previous
//
#include <hip/hip_runtime.h>
#include <hip/hip_bf16.h>
#include <math.h>

#define B_ 8
#define H_ 128
#define N_ 64
#define L_ 8192
#define MCH 64                 // chunk length
#define SCH (L_ / MCH)         // 128 chunks per sequence
#define EROW 136               // EBUF row stride (bf16 elems): 272 B, 16B-aligned

typedef __attribute__((ext_vector_type(8))) short bf16x8;  // MFMA A/B frag (4 VGPR)
typedef __attribute__((ext_vector_type(4))) float f32x4;   // MFMA C/D frag

__device__ __forceinline__ float bf2f(ushort s) { return __uint_as_float(((uint)s) << 16); }
// packed RNE fp32x2 -> bf16x2 (v_cvt_pk_bf16_f32 on gfx950 via HIP intrinsic)
__device__ __forceinline__ uint packbf2(float a, float b) {
    __hip_bfloat162 h = __float22bfloat162_rn(make_float2(a, b));
    union { __hip_bfloat162 h2; uint u; } cv; cv.h2 = h;
    return cv.u;
}
__device__ __forceinline__ bf16x8 pack_bf8(float4 a, float4 b) {
    union { uint u[4]; bf16x8 v; } r;
    r.u[0] = packbf2(a.x, a.y); r.u[1] = packbf2(a.z, a.w);
    r.u[2] = packbf2(b.x, b.y); r.u[3] = packbf2(b.z, b.w);
    return r.v;
}

// ===================== P0: build per-head T, P, Q, r^M ======================
// Chain-free: r^d = exp(d*dre) * cis(d*dim) directly per element (matches the
// reference's exp(times*dA)). 256 threads/head: n = tid&63, g = tid>>6.
__global__ __launch_bounds__(256) void s4d_build(
    const float* __restrict__ A_re, const float* __restrict__ A_im,
    const float* __restrict__ C, const float* __restrict__ D,
    const float* __restrict__ log_delta,
    ushort* __restrict__ wsT, ushort* __restrict__ wsP,
    ushort* __restrict__ wsQ, float2* __restrict__ wsRM)
{
    __shared__ float kpart[64][65];
    __shared__ float kv[64];
    __shared__ uint  pbuf[64 * 68];

    const int h = blockIdx.x;
    const int tid = threadIdx.x;
    const int n = tid & 63;
    const int g = tid >> 6;

    float are = fminf(A_re[h * N_ + n], -1e-4f);
    float aim = A_im[h * N_ + n];
    float step = expf(log_delta[h]);
    float dre = step * are, dim = step * aim;
    float er = expf(dre);
    float rr = er * cosf(dim);
    float ri = er * sinf(dim);
    float cre = C[(h * N_ + n) * 2 + 0];
    float cim = C[(h * N_ + n) * 2 + 1];
    float inv  = 1.0f / (are * are + aim * aim);
    float numr = rr - 1.0f, numi = ri;
    float consr = (numr * are + numi * aim) * inv;
    float consi = (numi * are - numr * aim) * inv;
    float wr = cre * consr - cim * consi;
    float wi = cre * consi + cim * consr;
    float dval = D[h];

    auto rp = [&](float d, float& pr, float& pi) {
        float e = expf(d * dre);
        float s, c2; sincosf(d * dim, &s, &c2);
        pr = e * c2; pi = e * s;
    };

    // ---- K[d] = Re(sum_n w r^d): kpart[d][n], then column-sum ----
#pragma unroll
    for (int j = 0; j < 16; ++j) {
        int d = g * 16 + j;
        float pr, pi; rp((float)d, pr, pi);
        kpart[d][n] = wr * pr - wi * pi;
    }
    __syncthreads();
    if (tid < 64) {
        float s = 0.f;
#pragma unroll
        for (int m = 0; m < 64; ++m) s += kpart[tid][m];
        kv[tid] = s;
    }
    __syncthreads();

    // ---- T row n, cols [16g, 16g+16): K[n-t] + D on diag ----
    {
        uint tw[8];
#pragma unroll
        for (int i = 0; i < 8; ++i) {
            int t0 = g * 16 + 2 * i, t1 = t0 + 1;
            float v0 = (t0 <= n) ? kv[n - t0] : 0.f;
            float v1 = (t1 <= n) ? kv[n - t1] : 0.f;
            if (t0 == n) v0 += dval;
            if (t1 == n) v1 += dval;
            tw[i] = packbf2(v0, v1);
        }
        uint4* dT = (uint4*)(wsT + ((size_t)h * 64 + n) * 64 + g * 16);
        dT[0] = ((uint4*)tw)[0]; dT[1] = ((uint4*)tw)[1];
    }

    // ---- Q rows 2n (Re), 2n+1 (Im), cols [16g,16g+16): r^{63-t} ----
    {
        uint qr[8], qi[8];
#pragma unroll
        for (int i = 0; i < 8; ++i) {
            int t0 = g * 16 + 2 * i;
            float ar0, ai0, ar1, ai1;
            rp((float)(63 - t0), ar0, ai0);
            rp((float)(62 - t0), ar1, ai1);
            qr[i] = packbf2(ar0, ar1);
            qi[i] = packbf2(ai0, ai1);
        }
        uint4* dQ0 = (uint4*)(wsQ + ((size_t)h * 128 + 2 * n    ) * 64 + g * 16);
        uint4* dQ1 = (uint4*)(wsQ + ((size_t)h * 128 + 2 * n + 1) * 64 + g * 16);
        dQ0[0] = ((uint4*)qr)[0]; dQ0[1] = ((uint4*)qr)[1];
        dQ1[0] = ((uint4*)qi)[0]; dQ1[1] = ((uint4*)qi)[1];
    }

    // ---- P[j][2n] = Re(w r^{j+1}), [2n+1] = -Im(w r^{j+1}) via LDS transpose
#pragma unroll
    for (int i = 0; i < 16; ++i) {
        int j = g * 16 + i;
        float pr, pi; rp((float)(j + 1), pr, pi);
        float ur = wr * pr - wi * pi;
        float ui = wr * pi + wi * pr;
        pbuf[j * 68 + n] = packbf2(ur, -ui);
    }
    if (tid < 64) {
        float mr, mi; rp(64.f, mr, mi);
        wsRM[h * 64 + n] = make_float2(mr, mi);
    }
    __syncthreads();
    {
        uint4* dP = (uint4*)(wsP + ((size_t)h * 64 + n) * 128 + g * 32);
        const uint* src = &pbuf[n * 68 + g * 16];
        dP[0] = *(const uint4*)(src);
        dP[1] = *(const uint4*)(src + 4);
        dP[2] = *(const uint4*)(src + 8);
        dP[3] = *(const uint4*)(src + 12);
    }
}

// ===================== main: per-(b,h) fused A/B/C ==========================
__global__ __launch_bounds__(256, 4) void s4d_main(
    const float* __restrict__ x,
    const ushort* __restrict__ wsT, const ushort* __restrict__ wsP,
    const ushort* __restrict__ wsQ, const float2* __restrict__ wsRM,
    float* __restrict__ out)
{
    __shared__ ushort EBUF[SCH * EROW];          // 128 x 136 bf16 = 34.8 KB
    __shared__ float segr[4][64], segi[4][64];   // 2 KB

    const int seq = blockIdx.x;              // b*H + h; all b's of head h share an XCD
    const int h   = seq % H_;
    const int tid = threadIdx.x;
    const int w   = tid >> 6;                // wave 0..3 -> col-tiles 2w, 2w+1
    const int lane = tid & 63;
    const int n16 = lane & 15, q = lane >> 4;

    const float* xs = x + (size_t)seq * L_;

    // ---- X B-frags (kept in regs for phases A and C): 16 VGPRs ----
    bf16x8 xb[2][2];
#pragma unroll
    for (int ic = 0; ic < 2; ++ic) {
        int c = (2 * w + ic) * 16 + n16;     // chunk index = GEMM column
#pragma unroll
        for (int kc = 0; kc < 2; ++kc) {
            const float* p = xs + c * MCH + kc * 32 + q * 8;
            float4 f0 = *(const float4*)p;
            float4 f1 = *(const float4*)(p + 4);
            xb[ic][kc] = pack_bf8(f0, f1);
        }
    }

    // ---- Phase A: E = Q * X ----
    const ushort* Qh = wsQ + (size_t)h * 128 * 64;
#pragma unroll
    for (int rt = 0; rt < 8; ++rt) {
        bf16x8 a0 = *(const bf16x8*)(Qh + ((size_t)(rt * 16 + n16)) * 64 +      q * 8);
        bf16x8 a1 = *(const bf16x8*)(Qh + ((size_t)(rt * 16 + n16)) * 64 + 32 + q * 8);
#pragma unroll
        for (int ic = 0; ic < 2; ++ic) {
            f32x4 acc = {0.f, 0.f, 0.f, 0.f};
            acc = __builtin_amdgcn_mfma_f32_16x16x32_bf16(a0, xb[ic][0], acc, 0, 0, 0);
            acc = __builtin_amdgcn_mfma_f32_16x16x32_bf16(a1, xb[ic][1], acc, 0, 0, 0);
            int c = (2 * w + ic) * 16 + n16;
            uint2 st = make_uint2(packbf2(acc[0], acc[1]), packbf2(acc[2], acc[3]));
            *(uint2*)&EBUF[c * EROW + rt * 16 + q * 4] = st;
        }
    }
    __syncthreads();

    // ---- Phase B: segmented exclusive chunk scan, all 256 threads ----
    {
        const int nB = tid & 63, gB = tid >> 6;
        float2 rm = wsRM[h * 64 + nB];
        float mr = rm.x, mi = rm.y;
        float m32r = mr, m32i = mi;          // r^2048 via 5 squarings
#pragma unroll
        for (int k = 0; k < 5; ++k) {
            float tr = m32r * m32r - m32i * m32i, ti = 2.f * m32r * m32i;
            m32r = tr; m32i = ti;
        }
        float sr = 0.f, si = 0.f;            // pass 1: zero-init segment end
#pragma unroll
        for (int j = 0; j < 32; ++j) {
            uint e = *(const uint*)&EBUF[(gB * 32 + j) * EROW + 2 * nB];
            float er2 = bf2f((ushort)(e & 0xffffu)), ei2 = bf2f((ushort)(e >> 16));
            float nr = er2 + mr * sr - mi * si;
            float ni = ei2 + mr * si + mi * sr;
            sr = nr; si = ni;
        }
        segr[gB][nB] = sr; segi[gB][nB] = si;
        __syncthreads();
        float pr2 = 0.f, pi2 = 0.f;          // exclusive prefix over segments
        for (int gp = 0; gp < gB; ++gp) {
            float Er = segr[gp][nB], Ei = segi[gp][nB];
            float nr = Er + m32r * pr2 - m32i * pi2;
            float ni = Ei + m32r * pi2 + m32i * pr2;
            pr2 = nr; pi2 = ni;
        }
        sr = pr2; si = pi2;                  // pass 2: replay, write SV in place
#pragma unroll
        for (int j = 0; j < 32; ++j) {
            uint* ep = (uint*)&EBUF[(gB * 32 + j) * EROW + 2 * nB];
            uint e = *ep;
            float er2 = bf2f((ushort)(e & 0xffffu)), ei2 = bf2f((ushort)(e >> 16));
            *ep = packbf2(sr, si);
            float nr = er2 + mr * sr - mi * si;
            float ni = ei2 + mr * si + mi * sr;
            sr = nr; si = ni;
        }
    }
    __syncthreads();

    // ---- Phase C: OUT = T*X + P*SV  (svb transient per-ic: low VGPR peak) ---
    const ushort* Th = wsT + (size_t)h * 64 * 64;
    const ushort* Ph = wsP + (size_t)h * 64 * 128;
    float* op = out + (size_t)seq * L_;
#pragma unroll
    for (int rt = 0; rt < 4; ++rt) {
        bf16x8 t0 = *(const bf16x8*)(Th + ((size_t)(rt * 16 + n16)) * 64 +      q * 8);
        bf16x8 t1 = *(const bf16x8*)(Th + ((size_t)(rt * 16 + n16)) * 64 + 32 + q * 8);
        bf16x8 p0 = *(const bf16x8*)(Ph + ((size_t)(rt * 16 + n16)) * 128 +       q * 8);
        bf16x8 p1 = *(const bf16x8*)(Ph + ((size_t)(rt * 16 + n16)) * 128 +  32 + q * 8);
        bf16x8 p2 = *(const bf16x8*)(Ph + ((size_t)(rt * 16 + n16)) * 128 +  64 + q * 8);
        bf16x8 p3 = *(const bf16x8*)(Ph + ((size_t)(rt * 16 + n16)) * 128 +  96 + q * 8);
#pragma unroll
        for (int ic = 0; ic < 2; ++ic) {
            int c = (2 * w + ic) * 16 + n16;
            f32x4 acc = {0.f, 0.f, 0.f, 0.f};
            acc = __builtin_amdgcn_mfma_f32_16x16x32_bf16(t0, xb[ic][0], acc, 0, 0, 0);
            acc = __builtin_amdgcn_mfma_f32_16x16x32_bf16(t1, xb[ic][1], acc, 0, 0, 0);
            bf16x8 s0 = *(const bf16x8*)&EBUF[c * EROW +       q * 8];
            bf16x8 s1 = *(const bf16x8*)&EBUF[c * EROW +  32 + q * 8];
            bf16x8 s2 = *(const bf16x8*)&EBUF[c * EROW +  64 + q * 8];
            bf16x8 s3 = *(const bf16x8*)&EBUF[c * EROW +  96 + q * 8];
            acc = __builtin_amdgcn_mfma_f32_16x16x32_bf16(p0, s0, acc, 0, 0, 0);
            acc = __builtin_amdgcn_mfma_f32_16x16x32_bf16(p1, s1, acc, 0, 0, 0);
            acc = __builtin_amdgcn_mfma_f32_16x16x32_bf16(p2, s2, acc, 0, 0, 0);
            acc = __builtin_amdgcn_mfma_f32_16x16x32_bf16(p3, s3, acc, 0, 0, 0);
            float4 o = make_float4(acc[0], acc[1], acc[2], acc[3]);
            *(float4*)(op + c * MCH + rt * 16 + q * 4) = o;
        }
    }
}

extern "C" void kernel_launch(void* const* d_in, const int* in_sizes, int n_in,
                              void* d_out, int out_size, void* d_ws, size_t ws_size,
                              hipStream_t stream)
{
    const float* x  = (const float*)d_in[0];
    const float* Ar = (const float*)d_in[1];
    const float* Ai = (const float*)d_in[2];
    const float* C  = (const float*)d_in[3];
    const float* D  = (const float*)d_in[4];
    const float* ld = (const float*)d_in[5];
    float* out = (float*)d_out;

    ushort* wsT = (ushort*)d_ws;                 // 128*64*64   bf16 = 1 MB
    ushort* wsP = wsT + (size_t)128 * 64 * 64;   // 128*64*128  bf16 = 2 MB
    ushort* wsQ = wsP + (size_t)128 * 64 * 128;  // 128*128*64  bf16 = 2 MB
    float2* wsRM = (float2*)(wsQ + (size_t)128 * 128 * 64);  // 64 KB

    hipLaunchKernelGGL(s4d_build, dim3(H_), dim3(256), 0, stream,
                       Ar, Ai, C, D, ld, wsT, wsP, wsQ, wsRM);
    hipLaunchKernelGGL(s4d_main, dim3(B_ * H_), dim3(256), 0, stream,
                       x, wsT, wsP, wsQ, wsRM, out);
}

// Round 6
// 112.980 us; speedup vs baseline: 2.5400x; 1.0744x over previous
//
#include <hip/hip_runtime.h>
#include <hip/hip_bf16.h>
#include <math.h>

#define B_ 8
#define H_ 128
#define N_ 64
#define L_ 8192
#define MCH 64                 // chunk length
#define SCH (L_ / MCH)         // 128 chunks per sequence
#define EROW 136               // EBUF row stride (bf16 elems): 272 B, 16B-aligned

typedef __attribute__((ext_vector_type(8))) short bf16x8;  // MFMA A/B frag (4 VGPR)
typedef __attribute__((ext_vector_type(4))) float f32x4;   // MFMA C/D frag

__device__ __forceinline__ float bf2f(ushort s) { return __uint_as_float(((uint)s) << 16); }
// packed RNE fp32x2 -> bf16x2 (v_cvt_pk_bf16_f32 on gfx950)
__device__ __forceinline__ uint packbf2(float a, float b) {
    __hip_bfloat162 h = __float22bfloat162_rn(make_float2(a, b));
    union { __hip_bfloat162 h2; uint u; } cv; cv.h2 = h;
    return cv.u;
}
__device__ __forceinline__ bf16x8 pack_bf8(float4 a, float4 b) {
    union { uint u[4]; bf16x8 v; } r;
    r.u[0] = packbf2(a.x, a.y); r.u[1] = packbf2(a.z, a.w);
    r.u[2] = packbf2(b.x, b.y); r.u[3] = packbf2(b.z, b.w);
    return r.v;
}

// ===================== P0: build per-head T, P, Q, r^M ======================
// Chain-free r^d = exp(d*dre) * cis(d*dim), computed with HARDWARE fast
// transcendentals (v_exp/v_sin/v_cos): results are immediately bf16-rounded
// (4e-3 rel), so the ~1e-5 fast-path error is invisible. Precise libm only
// for r^1 (feeds w) and r^64 (feeds the fp32 chunk scan).
__global__ __launch_bounds__(256) void s4d_build(
    const float* __restrict__ A_re, const float* __restrict__ A_im,
    const float* __restrict__ C, const float* __restrict__ D,
    const float* __restrict__ log_delta,
    ushort* __restrict__ wsT, ushort* __restrict__ wsP,
    ushort* __restrict__ wsQ, float2* __restrict__ wsRM)
{
    __shared__ float kpart[64][65];
    __shared__ float kv[64];
    __shared__ uint  pbuf[64 * 68];

    const int h = blockIdx.x;
    const int tid = threadIdx.x;
    const int n = tid & 63;
    const int g = tid >> 6;

    float are = fminf(A_re[h * N_ + n], -1e-4f);
    float aim = A_im[h * N_ + n];
    float step = expf(log_delta[h]);
    float dre = step * are, dim = step * aim;
    // precise r (feeds w and the scan multiplier chain)
    float er = expf(dre);
    float sd, cd; sincosf(dim, &sd, &cd);
    float rr = er * cd;
    float ri = er * sd;
    float cre = C[(h * N_ + n) * 2 + 0];
    float cim = C[(h * N_ + n) * 2 + 1];
    float inv  = 1.0f / (are * are + aim * aim);
    float numr = rr - 1.0f, numi = ri;
    float consr = (numr * are + numi * aim) * inv;
    float consi = (numi * are - numr * aim) * inv;
    float wr = cre * consr - cim * consi;
    float wi = cre * consi + cim * consr;
    float dval = D[h];

    // fast power: hardware transcendentals (~15 instr vs ~150 libm)
    auto rp = [&](float d, float& pr, float& pi) {
        float e = __expf(d * dre);
        float ang = d * dim;
        float s = __sinf(ang), c2 = __cosf(ang);
        pr = e * c2; pi = e * s;
    };

    // ---- K[d] = Re(sum_n w r^d): kpart[d][n], then column-sum ----
#pragma unroll
    for (int j = 0; j < 16; ++j) {
        int d = g * 16 + j;
        float pr, pi; rp((float)d, pr, pi);
        kpart[d][n] = wr * pr - wi * pi;
    }
    __syncthreads();
    if (tid < 64) {
        float s = 0.f;
#pragma unroll
        for (int m = 0; m < 64; ++m) s += kpart[tid][m];
        kv[tid] = s;
    }
    __syncthreads();

    // ---- T row n, cols [16g, 16g+16): K[n-t] + D on diag ----
    {
        uint tw[8];
#pragma unroll
        for (int i = 0; i < 8; ++i) {
            int t0 = g * 16 + 2 * i, t1 = t0 + 1;
            float v0 = (t0 <= n) ? kv[n - t0] : 0.f;
            float v1 = (t1 <= n) ? kv[n - t1] : 0.f;
            if (t0 == n) v0 += dval;
            if (t1 == n) v1 += dval;
            tw[i] = packbf2(v0, v1);
        }
        uint4* dT = (uint4*)(wsT + ((size_t)h * 64 + n) * 64 + g * 16);
        dT[0] = ((uint4*)tw)[0]; dT[1] = ((uint4*)tw)[1];
    }

    // ---- Q rows 2n (Re), 2n+1 (Im), cols [16g,16g+16): r^{63-t} ----
    {
        uint qr[8], qi[8];
#pragma unroll
        for (int i = 0; i < 8; ++i) {
            int t0 = g * 16 + 2 * i;
            float ar0, ai0, ar1, ai1;
            rp((float)(63 - t0), ar0, ai0);
            rp((float)(62 - t0), ar1, ai1);
            qr[i] = packbf2(ar0, ar1);
            qi[i] = packbf2(ai0, ai1);
        }
        uint4* dQ0 = (uint4*)(wsQ + ((size_t)h * 128 + 2 * n    ) * 64 + g * 16);
        uint4* dQ1 = (uint4*)(wsQ + ((size_t)h * 128 + 2 * n + 1) * 64 + g * 16);
        dQ0[0] = ((uint4*)qr)[0]; dQ0[1] = ((uint4*)qr)[1];
        dQ1[0] = ((uint4*)qi)[0]; dQ1[1] = ((uint4*)qi)[1];
    }

    // ---- P[j][2n] = Re(w r^{j+1}), [2n+1] = -Im(w r^{j+1}) via LDS transpose
#pragma unroll
    for (int i = 0; i < 16; ++i) {
        int j = g * 16 + i;
        float pr, pi; rp((float)(j + 1), pr, pi);
        float ur = wr * pr - wi * pi;
        float ui = wr * pi + wi * pr;
        pbuf[j * 68 + n] = packbf2(ur, -ui);
    }
    if (tid < 64) {
        // precise r^64: 6 squarings of the precise r (feeds fp32 scan)
        float mr = rr, mi = ri;
#pragma unroll
        for (int k = 0; k < 6; ++k) { float tr = mr*mr - mi*mi, ti = 2.f*mr*mi; mr = tr; mi = ti; }
        wsRM[h * 64 + n] = make_float2(mr, mi);
    }
    __syncthreads();
    {
        uint4* dP = (uint4*)(wsP + ((size_t)h * 64 + n) * 128 + g * 32);
        const uint* src = &pbuf[n * 68 + g * 16];
        dP[0] = *(const uint4*)(src);
        dP[1] = *(const uint4*)(src + 4);
        dP[2] = *(const uint4*)(src + 8);
        dP[3] = *(const uint4*)(src + 12);
    }
}

// ===================== main: per-(b,h) fused A/B/C ==========================
__global__ __launch_bounds__(256, 4) void s4d_main(
    const float* __restrict__ x,
    const ushort* __restrict__ wsT, const ushort* __restrict__ wsP,
    const ushort* __restrict__ wsQ, const float2* __restrict__ wsRM,
    float* __restrict__ out)
{
    __shared__ ushort EBUF[SCH * EROW];          // 128 x 136 bf16 = 34.8 KB
    __shared__ float segr[4][64], segi[4][64];   // 2 KB

    const int seq = blockIdx.x;              // b*H + h; all b's of head h share an XCD
    const int h   = seq % H_;
    const int tid = threadIdx.x;
    const int w   = tid >> 6;                // wave 0..3 -> col-tiles 2w, 2w+1
    const int lane = tid & 63;
    const int n16 = lane & 15, q = lane >> 4;

    const float* xs = x + (size_t)seq * L_;

    // ---- X B-frags (kept in regs for phases A and C): 16 VGPRs ----
    bf16x8 xb[2][2];
#pragma unroll
    for (int ic = 0; ic < 2; ++ic) {
        int c = (2 * w + ic) * 16 + n16;     // chunk index = GEMM column
#pragma unroll
        for (int kc = 0; kc < 2; ++kc) {
            const float* p = xs + c * MCH + kc * 32 + q * 8;
            float4 f0 = *(const float4*)p;
            float4 f1 = *(const float4*)(p + 4);
            xb[ic][kc] = pack_bf8(f0, f1);
        }
    }

    // ---- Phase A: E = Q * X ----
    const ushort* Qh = wsQ + (size_t)h * 128 * 64;
#pragma unroll
    for (int rt = 0; rt < 8; ++rt) {
        bf16x8 a0 = *(const bf16x8*)(Qh + ((size_t)(rt * 16 + n16)) * 64 +      q * 8);
        bf16x8 a1 = *(const bf16x8*)(Qh + ((size_t)(rt * 16 + n16)) * 64 + 32 + q * 8);
#pragma unroll
        for (int ic = 0; ic < 2; ++ic) {
            f32x4 acc = {0.f, 0.f, 0.f, 0.f};
            acc = __builtin_amdgcn_mfma_f32_16x16x32_bf16(a0, xb[ic][0], acc, 0, 0, 0);
            acc = __builtin_amdgcn_mfma_f32_16x16x32_bf16(a1, xb[ic][1], acc, 0, 0, 0);
            int c = (2 * w + ic) * 16 + n16;
            uint2 st = make_uint2(packbf2(acc[0], acc[1]), packbf2(acc[2], acc[3]));
            *(uint2*)&EBUF[c * EROW + rt * 16 + q * 4] = st;
        }
    }
    __syncthreads();

    // ---- Phase B: segmented exclusive chunk scan, all 256 threads ----
    {
        const int nB = tid & 63, gB = tid >> 6;
        float2 rm = wsRM[h * 64 + nB];
        float mr = rm.x, mi = rm.y;
        float m32r = mr, m32i = mi;          // r^2048 via 5 squarings
#pragma unroll
        for (int k = 0; k < 5; ++k) {
            float tr = m32r * m32r - m32i * m32i, ti = 2.f * m32r * m32i;
            m32r = tr; m32i = ti;
        }
        float sr = 0.f, si = 0.f;            // pass 1: zero-init segment end
#pragma unroll
        for (int j = 0; j < 32; ++j) {
            uint e = *(const uint*)&EBUF[(gB * 32 + j) * EROW + 2 * nB];
            float er2 = bf2f((ushort)(e & 0xffffu)), ei2 = bf2f((ushort)(e >> 16));
            float nr = er2 + mr * sr - mi * si;
            float ni = ei2 + mr * si + mi * sr;
            sr = nr; si = ni;
        }
        segr[gB][nB] = sr; segi[gB][nB] = si;
        __syncthreads();
        float pr2 = 0.f, pi2 = 0.f;          // exclusive prefix over segments
        for (int gp = 0; gp < gB; ++gp) {
            float Er = segr[gp][nB], Ei = segi[gp][nB];
            float nr = Er + m32r * pr2 - m32i * pi2;
            float ni = Ei + m32r * pi2 + m32i * pr2;
            pr2 = nr; pi2 = ni;
        }
        sr = pr2; si = pi2;                  // pass 2: replay, write SV in place
#pragma unroll
        for (int j = 0; j < 32; ++j) {
            uint* ep = (uint*)&EBUF[(gB * 32 + j) * EROW + 2 * nB];
            uint e = *ep;
            float er2 = bf2f((ushort)(e & 0xffffu)), ei2 = bf2f((ushort)(e >> 16));
            *ep = packbf2(sr, si);
            float nr = er2 + mr * sr - mi * si;
            float ni = ei2 + mr * si + mi * sr;
            sr = nr; si = ni;
        }
    }
    __syncthreads();

    // ---- Phase C: OUT = T*X + P*SV  (dual accumulators: shorter MFMA chains)
    const ushort* Th = wsT + (size_t)h * 64 * 64;
    const ushort* Ph = wsP + (size_t)h * 64 * 128;
    float* op = out + (size_t)seq * L_;
#pragma unroll
    for (int rt = 0; rt < 4; ++rt) {
        bf16x8 t0 = *(const bf16x8*)(Th + ((size_t)(rt * 16 + n16)) * 64 +      q * 8);
        bf16x8 t1 = *(const bf16x8*)(Th + ((size_t)(rt * 16 + n16)) * 64 + 32 + q * 8);
        bf16x8 p0 = *(const bf16x8*)(Ph + ((size_t)(rt * 16 + n16)) * 128 +       q * 8);
        bf16x8 p1 = *(const bf16x8*)(Ph + ((size_t)(rt * 16 + n16)) * 128 +  32 + q * 8);
        bf16x8 p2 = *(const bf16x8*)(Ph + ((size_t)(rt * 16 + n16)) * 128 +  64 + q * 8);
        bf16x8 p3 = *(const bf16x8*)(Ph + ((size_t)(rt * 16 + n16)) * 128 +  96 + q * 8);
#pragma unroll
        for (int ic = 0; ic < 2; ++ic) {
            int c = (2 * w + ic) * 16 + n16;
            f32x4 accT = {0.f, 0.f, 0.f, 0.f};
            f32x4 accP = {0.f, 0.f, 0.f, 0.f};
            accT = __builtin_amdgcn_mfma_f32_16x16x32_bf16(t0, xb[ic][0], accT, 0, 0, 0);
            accP = __builtin_amdgcn_mfma_f32_16x16x32_bf16(p0,
                       *(const bf16x8*)&EBUF[c * EROW +       q * 8], accP, 0, 0, 0);
            accT = __builtin_amdgcn_mfma_f32_16x16x32_bf16(t1, xb[ic][1], accT, 0, 0, 0);
            accP = __builtin_amdgcn_mfma_f32_16x16x32_bf16(p1,
                       *(const bf16x8*)&EBUF[c * EROW +  32 + q * 8], accP, 0, 0, 0);
            accP = __builtin_amdgcn_mfma_f32_16x16x32_bf16(p2,
                       *(const bf16x8*)&EBUF[c * EROW +  64 + q * 8], accP, 0, 0, 0);
            accP = __builtin_amdgcn_mfma_f32_16x16x32_bf16(p3,
                       *(const bf16x8*)&EBUF[c * EROW +  96 + q * 8], accP, 0, 0, 0);
            float4 o = make_float4(accT[0] + accP[0], accT[1] + accP[1],
                                   accT[2] + accP[2], accT[3] + accP[3]);
            *(float4*)(op + c * MCH + rt * 16 + q * 4) = o;
        }
    }
}

extern "C" void kernel_launch(void* const* d_in, const int* in_sizes, int n_in,
                              void* d_out, int out_size, void* d_ws, size_t ws_size,
                              hipStream_t stream)
{
    const float* x  = (const float*)d_in[0];
    const float* Ar = (const float*)d_in[1];
    const float* Ai = (const float*)d_in[2];
    const float* C  = (const float*)d_in[3];
    const float* D  = (const float*)d_in[4];
    const float* ld = (const float*)d_in[5];
    float* out = (float*)d_out;

    ushort* wsT = (ushort*)d_ws;                 // 128*64*64   bf16 = 1 MB
    ushort* wsP = wsT + (size_t)128 * 64 * 64;   // 128*64*128  bf16 = 2 MB
    ushort* wsQ = wsP + (size_t)128 * 64 * 128;  // 128*128*64  bf16 = 2 MB
    float2* wsRM = (float2*)(wsQ + (size_t)128 * 128 * 64);  // 64 KB

    hipLaunchKernelGGL(s4d_build, dim3(H_), dim3(256), 0, stream,
                       Ar, Ai, C, D, ld, wsT, wsP, wsQ, wsRM);
    hipLaunchKernelGGL(s4d_main, dim3(B_ * H_), dim3(256), 0, stream,
                       x, wsT, wsP, wsQ, wsRM, out);
}